// Round 1
// baseline (61.664 us; speedup 1.0000x reference)
//
#include <hip/hip_runtime.h>

// FocalLoss, 2 categories, negative handling.
// Identity used: bce(-x, 1-y) == bce(x, y)  =>  focal_neg == focal elementwise.
// loss[row] = (label==0) ? sum_c focal : sum_c focal * repr_mask.
//
// Memory-bound: 112MB logit + 112MB mask + 16MB label read, 16MB write.
// Each thread processes 4 rows (28 elements) via 7x float4 / 7x int4 loads,
// 1x int4 label load, 1x float4 store — all 16B-aligned.

__device__ __forceinline__ float focal_elem(float x, bool y1) {
    float e  = __expf(-fabsf(x));        // exp(-|x|), in (0,1]
    float r  = 1.0f / (1.0f + e);        // 1/(1+e)
    float q  = e * r;                    // e/(1+e)
    bool xpos = (x >= 0.0f);
    float pt = (y1 == xpos) ? r : q;     // prob of true class, no cancellation
    float bce = -__logf(pt);
    float om  = 1.0f - pt;
    return om * om * bce;                // (1-pt)^GAMMA * bce, GAMMA=2
}

__global__ __launch_bounds__(256) void focal_loss_kernel(
    const float* __restrict__ logit,
    const int*   __restrict__ label,
    const int*   __restrict__ repr_mask,
    float*       __restrict__ out,
    int B)
{
    int t = blockIdx.x * blockDim.x + threadIdx.x;
    int nquad = B >> 2;  // full quads of 4 rows

    if (t < nquad) {
        // fast path: 4 full rows
        const float4* lg4 = reinterpret_cast<const float4*>(logit) + (size_t)t * 7;
        const int4*   mk4 = reinterpret_cast<const int4*>(repr_mask) + (size_t)t * 7;
        int4 lab4 = reinterpret_cast<const int4*>(label)[t];

        float v[28];
        int   mk[28];
#pragma unroll
        for (int j = 0; j < 7; ++j) {
            float4 a = lg4[j];
            v[4*j+0] = a.x; v[4*j+1] = a.y; v[4*j+2] = a.z; v[4*j+3] = a.w;
            int4 b = mk4[j];
            mk[4*j+0] = b.x; mk[4*j+1] = b.y; mk[4*j+2] = b.z; mk[4*j+3] = b.w;
        }
        int labs[4] = {lab4.x, lab4.y, lab4.z, lab4.w};

        float res[4];
#pragma unroll
        for (int r = 0; r < 4; ++r) {
            bool y1 = (labs[r] != 0);
            float tot = 0.0f, msum = 0.0f;
#pragma unroll
            for (int c = 0; c < 7; ++c) {
                float f = focal_elem(v[r*7 + c], y1);
                tot  += f;
                msum += mk[r*7 + c] ? f : 0.0f;
            }
            res[r] = y1 ? msum : tot;
        }
        float4 o = make_float4(res[0], res[1], res[2], res[3]);
        reinterpret_cast<float4*>(out)[t] = o;
    } else if (t == nquad && (B & 3)) {
        // tail rows (B not divisible by 4) — scalar path
        for (int row = nquad * 4; row < B; ++row) {
            bool y1 = (label[row] != 0);
            float tot = 0.0f, msum = 0.0f;
            for (int c = 0; c < 7; ++c) {
                float f = focal_elem(logit[(size_t)row * 7 + c], y1);
                tot  += f;
                msum += repr_mask[(size_t)row * 7 + c] ? f : 0.0f;
            }
            out[row] = y1 ? msum : tot;
        }
    }
}

extern "C" void kernel_launch(void* const* d_in, const int* in_sizes, int n_in,
                              void* d_out, int out_size, void* d_ws, size_t ws_size,
                              hipStream_t stream) {
    const float* logit     = (const float*)d_in[0];
    const int*   label     = (const int*)d_in[1];
    const int*   repr_mask = (const int*)d_in[2];
    float*       out       = (float*)d_out;

    int B = in_sizes[1];                 // label has B elements
    int nquad = B >> 2;
    int nthreads = nquad + ((B & 3) ? 1 : 0);
    int blocks = (nthreads + 255) / 256;

    focal_loss_kernel<<<blocks, 256, 0, stream>>>(logit, label, repr_mask, out, B);
}

// Round 2
// 46.845 us; speedup vs baseline: 1.3163x; 1.3163x over previous
//
#include <hip/hip_runtime.h>

// FocalLoss, 2 categories, negative handling.
// Identity: bce(-x, 1-y) == bce(x, y)  =>  focal_neg == focal elementwise.
// loss[row] = (label!=0) ? sum_c focal*mask : sum_c focal.
//
// Round 1 -> 2: fix uncoalesced AoS loads (7 consecutive float4 per thread =
// 112B lane stride = 64 cachelines per load instr). Stage each block's chunk
// through 28KB LDS with lane-contiguous global loads, redistribute per-row
// from LDS (stride-28-dword reads = 2-way bank aliasing, free). One LDS
// buffer reused for logit then mask; focal math overlaps mask staging.

#define TPB 256
#define F4PB (TPB * 7)   // float4s per block chunk (256 quad-rows)

__device__ __forceinline__ float focal_elem(float x, bool y1) {
    float e  = __expf(-fabsf(x));        // exp(-|x|), in (0,1]
    float r  = 1.0f / (1.0f + e);        // 1/(1+e)
    float q  = e * r;                    // e/(1+e)
    bool xpos = (x >= 0.0f);
    float pt = (y1 == xpos) ? r : q;     // prob of true class, no cancellation
    float bce = -__logf(pt);
    float om  = 1.0f - pt;
    return om * om * bce;                // (1-pt)^2 * bce
}

__global__ __launch_bounds__(TPB) void focal_loss_kernel(
    const float* __restrict__ logit,
    const int*   __restrict__ label,
    const int*   __restrict__ repr_mask,
    float*       __restrict__ out,
    int B)
{
    __shared__ uint4 lds[F4PB];          // 28 KiB, reused logit -> mask

    const int Q   = B >> 2;              // quad-rows
    const int tid = threadIdx.x;
    const int q0  = blockIdx.x * TPB;
    const int nq  = min(TPB, Q - q0);
    const int nf4 = nq * 7;
    const bool active = tid < nq;

    const uint4* lg4 = reinterpret_cast<const uint4*>(logit)     + (size_t)q0 * 7;
    const uint4* mk4 = reinterpret_cast<const uint4*>(repr_mask) + (size_t)q0 * 7;

    // labels: coalesced int4 per thread (one per quad-row)
    int4 lab4 = make_int4(0, 0, 0, 0);
    if (active) lab4 = reinterpret_cast<const int4*>(label)[q0 + tid];

    // ---- stage logit chunk, lane-contiguous ----
#pragma unroll
    for (int k = 0; k < 7; ++k) {
        int idx = tid + k * TPB;
        if (idx < nf4) lds[idx] = lg4[idx];
    }
    __syncthreads();

    bool y1[4] = { lab4.x != 0, lab4.y != 0, lab4.z != 0, lab4.w != 0 };
    float f[28];
    if (active) {
#pragma unroll
        for (int j = 0; j < 7; ++j) {
            uint4 u = lds[tid * 7 + j];
            float4 a = *reinterpret_cast<float4*>(&u);
            f[4*j+0] = a.x; f[4*j+1] = a.y; f[4*j+2] = a.z; f[4*j+3] = a.w;
        }
#pragma unroll
        for (int i = 0; i < 28; ++i)     // i/7 is compile-time per unrolled iter
            f[i] = focal_elem(f[i], y1[i / 7]);
    }
    __syncthreads();                     // all LDS reads done before overwrite

    // ---- stage mask chunk (focal math above overlaps these loads) ----
#pragma unroll
    for (int k = 0; k < 7; ++k) {
        int idx = tid + k * TPB;
        if (idx < nf4) lds[idx] = mk4[idx];
    }
    __syncthreads();

    if (active) {
        float res[4] = {0.f, 0.f, 0.f, 0.f};
#pragma unroll
        for (int j = 0; j < 7; ++j) {
            uint4 m = lds[tid * 7 + j];
            unsigned mm[4] = { m.x, m.y, m.z, m.w };
#pragma unroll
            for (int k = 0; k < 4; ++k) {
                int i = 4*j + k;
                int r = i / 7;           // compile-time
                bool keep = y1[r] ? (mm[k] != 0) : true;
                res[r] += keep ? f[i] : 0.0f;
            }
        }
        reinterpret_cast<float4*>(out)[q0 + tid] =
            make_float4(res[0], res[1], res[2], res[3]);
    }

    // scalar tail for B % 4 != 0 (not hit for B = 4M)
    if ((B & 3) && blockIdx.x == 0 && tid == 0) {
        for (int row = Q * 4; row < B; ++row) {
            bool yy = (label[row] != 0);
            float tot = 0.f, ms = 0.f;
            for (int c = 0; c < 7; ++c) {
                float ff = focal_elem(logit[(size_t)row * 7 + c], yy);
                tot += ff;
                ms  += repr_mask[(size_t)row * 7 + c] ? ff : 0.f;
            }
            out[row] = yy ? ms : tot;
        }
    }
}

extern "C" void kernel_launch(void* const* d_in, const int* in_sizes, int n_in,
                              void* d_out, int out_size, void* d_ws, size_t ws_size,
                              hipStream_t stream) {
    const float* logit     = (const float*)d_in[0];
    const int*   label     = (const int*)d_in[1];
    const int*   repr_mask = (const int*)d_in[2];
    float*       out       = (float*)d_out;

    int B = in_sizes[1];                 // label has B elements
    int Q = B >> 2;
    int blocks = (Q + TPB - 1) / TPB;
    if (blocks < 1) blocks = 1;

    focal_loss_kernel<<<blocks, TPB, 0, stream>>>(logit, label, repr_mask, out, B);
}

// Round 3
// 46.422 us; speedup vs baseline: 1.3283x; 1.0091x over previous
//
#include <hip/hip_runtime.h>
#include <stdint.h>

// FocalLoss, 2 categories, negative handling.
// Identity: bce(-x, 1-y) == bce(x, y)  =>  focal_neg == focal elementwise.
// loss[row] = (label!=0) ? sum_c focal*mask : sum_c focal.
//
// Round 2 -> 3: remove all block barriers. Each wave stages its own 64
// quad-rows (448 uint4 = 7 KiB) in a wave-private LDS region:
//   - logit: global_load_lds width=16 (linear dest = lane*16, its native
//     pattern; no VGPR round-trip)
//   - mask + label: coalesced register loads, issued at the same time
//   - one vmcnt(0), then ds_read logit / ds_write mask (rebounce) / focal
//     math / ds_read mask / reduce. Same-wave DS ops process in order; the
//     compiler's lgkmcnt waits + LDS aliasing preserve correctness with no
//     s_barrier anywhere.
// 28 KiB/block -> 5 blocks/CU -> 20 waves/CU; __launch_bounds__(256,5)
// keeps VGPRs <= 102 so LDS stays the only occupancy limiter.

#define TPB 256
#define U4W 448   // uint4 per wave region: 64 quad-rows * 7

#define GLOAD_LDS16(gp, lp)                                         \
    __builtin_amdgcn_global_load_lds(                               \
        (const __attribute__((address_space(1))) void*)(gp),        \
        (__attribute__((address_space(3))) void*)(lp), 16, 0, 0)

__device__ __forceinline__ float focal_elem(float x, bool y1) {
    float e  = __expf(-fabsf(x));        // exp(-|x|), in (0,1]
    float r  = 1.0f / (1.0f + e);        // 1/(1+e)
    float q  = e * r;                    // e/(1+e)
    bool xpos = (x >= 0.0f);
    float pt = (y1 == xpos) ? r : q;     // prob of true class, no cancellation
    float bce = -__logf(pt);
    float om  = 1.0f - pt;
    return om * om * bce;                // (1-pt)^2 * bce
}

__global__ __launch_bounds__(TPB, 5) void focal_loss_kernel(
    const float* __restrict__ logit,
    const int*   __restrict__ label,
    const int*   __restrict__ repr_mask,
    float*       __restrict__ out,
    int B)
{
    __shared__ uint4 lds[4][U4W];        // 28 KiB, one 7 KiB region per wave

    const int Q    = B >> 2;             // quad-rows
    const int tid  = threadIdx.x;
    const int lane = tid & 63;
    const int w    = tid >> 6;
    const int q0   = blockIdx.x * TPB + w * 64;   // this wave's first quad-row

    uint4* wbuf = lds[w];

    if (q0 + 64 <= Q) {
        // ---- full wave: 64 quad-rows ----
        const uint4* lg4 = reinterpret_cast<const uint4*>(logit)     + (size_t)q0 * 7;
        const uint4* mk4 = reinterpret_cast<const uint4*>(repr_mask) + (size_t)q0 * 7;

        // issue ALL global traffic up front
#pragma unroll
        for (int k = 0; k < 7; ++k)
            GLOAD_LDS16(lg4 + k * 64 + lane, wbuf + k * 64);

        int4 lab4 = reinterpret_cast<const int4*>(label)[q0 + lane];
        uint4 mreg[7];
#pragma unroll
        for (int k = 0; k < 7; ++k)
            mreg[k] = mk4[k * 64 + lane];

        // logit bytes are in LDS once vmcnt drains (mask regs drain too)
        asm volatile("s_waitcnt vmcnt(0)" ::: "memory");

        // gather this thread's 4 rows (28 floats) from LDS
        float f[28];
#pragma unroll
        for (int j = 0; j < 7; ++j) {
            uint4 u = wbuf[lane * 7 + j];
            float4 a = *reinterpret_cast<float4*>(&u);
            f[4*j+0] = a.x; f[4*j+1] = a.y; f[4*j+2] = a.z; f[4*j+3] = a.w;
        }

        // rebounce mask into same region (same-wave DS pipe is in-order;
        // reads above already issued, data consumed via lgkmcnt before use)
#pragma unroll
        for (int k = 0; k < 7; ++k)
            wbuf[k * 64 + lane] = mreg[k];

        bool y1[4] = { lab4.x != 0, lab4.y != 0, lab4.z != 0, lab4.w != 0 };
#pragma unroll
        for (int i = 0; i < 28; ++i)     // i/7 is compile-time per unrolled iter
            f[i] = focal_elem(f[i], y1[i / 7]);

        float res[4] = {0.f, 0.f, 0.f, 0.f};
#pragma unroll
        for (int j = 0; j < 7; ++j) {
            uint4 m = wbuf[lane * 7 + j];
            unsigned mm[4] = { m.x, m.y, m.z, m.w };
#pragma unroll
            for (int k = 0; k < 4; ++k) {
                int i = 4*j + k;
                int r = i / 7;           // compile-time
                bool keep = y1[r] ? (mm[k] != 0) : true;
                res[r] += keep ? f[i] : 0.0f;
            }
        }
        reinterpret_cast<float4*>(out)[q0 + lane] =
            make_float4(res[0], res[1], res[2], res[3]);
    } else if (q0 < Q) {
        // ---- partial wave (not hit for B = 4M): scalar per-lane path ----
        int r4 = q0 + lane;
        if (r4 < Q) {
            int lab = label[r4 * 4];     // unused dummy to keep shape; real below
            (void)lab;
            float res[4];
#pragma unroll
            for (int r = 0; r < 4; ++r) {
                int row = r4 * 4 + r;
                bool yy = (label[row] != 0);
                float tot = 0.f, ms = 0.f;
                for (int c = 0; c < 7; ++c) {
                    float ff = focal_elem(logit[(size_t)row * 7 + c], yy);
                    tot += ff;
                    ms  += repr_mask[(size_t)row * 7 + c] ? ff : 0.f;
                }
                res[r] = yy ? ms : tot;
            }
            reinterpret_cast<float4*>(out)[r4] =
                make_float4(res[0], res[1], res[2], res[3]);
        }
    }

    // scalar tail for B % 4 != 0 (not hit for B = 4M)
    if ((B & 3) && blockIdx.x == 0 && tid == 0) {
        for (int row = Q * 4; row < B; ++row) {
            bool yy = (label[row] != 0);
            float tot = 0.f, ms = 0.f;
            for (int c = 0; c < 7; ++c) {
                float ff = focal_elem(logit[(size_t)row * 7 + c], yy);
                tot += ff;
                ms  += repr_mask[(size_t)row * 7 + c] ? ff : 0.f;
            }
            out[row] = yy ? ms : tot;
        }
    }
}

extern "C" void kernel_launch(void* const* d_in, const int* in_sizes, int n_in,
                              void* d_out, int out_size, void* d_ws, size_t ws_size,
                              hipStream_t stream) {
    const float* logit     = (const float*)d_in[0];
    const int*   label     = (const int*)d_in[1];
    const int*   repr_mask = (const int*)d_in[2];
    float*       out       = (float*)d_out;

    int B = in_sizes[1];                 // label has B elements
    int Q = B >> 2;
    int blocks = (Q + TPB - 1) / TPB;
    if (blocks < 1) blocks = 1;

    focal_loss_kernel<<<blocks, TPB, 0, stream>>>(logit, label, repr_mask, out, B);
}

// Round 4
// 45.283 us; speedup vs baseline: 1.3618x; 1.0252x over previous
//
#include <hip/hip_runtime.h>

// FocalLoss, 2 categories, negative handling.
// Identity: bce(-x,1-y) == bce(x,y) => focal_neg == focal elementwise.
// loss[row] = (label!=0) ? sum_c f1*mask : sum_c f0   (f_y = focal with label y)
//
// Round 3 -> 4: transpose PARTIAL SUMS, not inputs.
//  - One-log trick: r=1/(1+e), q=e*r, r+q=1, -log r = log(1+e)=Lg,
//    -log q = |x|+Lg  =>  f(pt=r)=q^2*Lg, f(pt=q)=r^2*(|x|+Lg).
//    Both label flavors from 1 exp + 1 rcp + 1 log.
//  - Each lane loads uint4 #(k*64+lane) of logit+mask (coalesced, registers),
//    reduces 4 elements into rowA/rowB partials (boundary mu=(4u)%7, updated
//    incrementally), stages ONE float4 (A0,A1,B0,B1) per step. 56 LDS
//    dwords/lane total vs 112 before; both phases 2-way bank aliased (free).
//  - Read side: 7x ds_read_b128 at lane*7+i, compile-time i->row mapping,
//    label select, float4 store. Wave-private region, no barriers (same-wave
//    DS pipe is in-order; validated in round 3).
//  - __builtin_amdgcn_rcpf replaces the precise-div sequence (~8 ops/elem).

#define TPB 256

__device__ __forceinline__ void focal_both(float x, float& f0, float& f1) {
    float a  = fabsf(x);
    float e  = __expf(-a);                    // exp(-|x|) in (0,1]
    float r  = __builtin_amdgcn_rcpf(1.0f + e);
    float q  = e * r;                         // r+q == 1
    float Lg = __logf(1.0f + e);              // = -log r ;  -log q = a+Lg
    float tr = q * q * Lg;                    // focal when pt=r
    float tq = r * r * (a + Lg);              // focal when pt=q
    bool xpos = (x >= 0.0f);
    f1 = xpos ? tr : tq;                      // label==1
    f0 = xpos ? tq : tr;                      // label==0
}

__global__ __launch_bounds__(TPB, 4) void focal_loss_kernel(
    const float* __restrict__ logit,
    const int*   __restrict__ label,
    const int*   __restrict__ repr_mask,
    float*       __restrict__ out,
    int B)
{
    __shared__ float4 stage[4][448];          // 28 KiB, 7 KiB per wave

    const int tid  = threadIdx.x;
    const int L    = tid & 63;
    const int w    = tid >> 6;
    const int wc   = blockIdx.x * 4 + w;      // wave-chunk index: 256 rows
    const long R0  = (long)wc * 256;

    float4* wbuf = stage[w];

    if (R0 + 256 <= B) {
        // ---- fast path: full 256-row chunk = 448 uint4 of logit/mask ----
        const uint4* lg4 = reinterpret_cast<const uint4*>(logit)     + (size_t)wc * 448;
        const uint4* mk4 = reinterpret_cast<const uint4*>(repr_mask) + (size_t)wc * 448;

        uint4 lg[7], mk[7];
#pragma unroll
        for (int k = 0; k < 7; ++k) lg[k] = lg4[k * 64 + L];
#pragma unroll
        for (int k = 0; k < 7; ++k) mk[k] = mk4[k * 64 + L];
        int4 lab4 = reinterpret_cast<const int4*>(label)[(size_t)wc * 64 + L];

        // elementwise phase: mu = (4*u) mod 7 for u = k*64+L ; step +4 mod 7
        int mu = (4 * L) % 7;
#pragma unroll
        for (int k = 0; k < 7; ++k) {
            float4 xf = *reinterpret_cast<float4*>(&lg[k]);
            float xs[4] = { xf.x, xf.y, xf.z, xf.w };
            unsigned ms[4] = { mk[k].x, mk[k].y, mk[k].z, mk[k].w };

            float A0 = 0.f, A1 = 0.f, B0 = 0.f, B1 = 0.f;
#pragma unroll
            for (int j = 0; j < 4; ++j) {
                float f0, f1;
                focal_both(xs[j], f0, f1);
                float fm = ms[j] ? f1 : 0.0f;
                bool toB = (mu + j) >= 7;     // element belongs to rowA+1
                A0 += toB ? 0.0f : f0;
                B0 += toB ? f0   : 0.0f;
                A1 += toB ? 0.0f : fm;
                B1 += toB ? fm   : 0.0f;
            }
            wbuf[k * 64 + L] = make_float4(A0, A1, B0, B1);
            mu += 4; if (mu >= 7) mu -= 7;
        }

        // transpose-combine: u = 7L+i, rowA(u) = 4L + (4i)/7 (compile-time)
        float4 u0 = wbuf[L * 7 + 0];
        float4 u1 = wbuf[L * 7 + 1];
        float4 u2 = wbuf[L * 7 + 2];
        float4 u3 = wbuf[L * 7 + 3];
        float4 u4 = wbuf[L * 7 + 4];
        float4 u5 = wbuf[L * 7 + 5];
        float4 u6 = wbuf[L * 7 + 6];

        float t0_0 = u0.x + u1.x;             // row+0, unmasked (label 0)
        float t1_0 = u0.y + u1.y;             // row+0, masked   (label 1)
        float t0_1 = u1.z + u2.x + u3.x;      // row+1
        float t1_1 = u1.w + u2.y + u3.y;
        float t0_2 = u3.z + u4.x + u5.x;      // row+2
        float t1_2 = u3.w + u4.y + u5.y;
        float t0_3 = u5.z + u6.x;             // row+3
        float t1_3 = u5.w + u6.y;

        float4 res;
        res.x = (lab4.x != 0) ? t1_0 : t0_0;
        res.y = (lab4.y != 0) ? t1_1 : t0_1;
        res.z = (lab4.z != 0) ? t1_2 : t0_2;
        res.w = (lab4.w != 0) ? t1_3 : t0_3;
        reinterpret_cast<float4*>(out)[(size_t)wc * 64 + L] = res;
    } else if (R0 < B) {
        // ---- partial chunk (B % 256): per-lane scalar quad-rows ----
        long r4 = R0 / 4 + L;                 // quad-row index
        long Q  = B >> 2;
        if (r4 < Q) {
            float res[4];
#pragma unroll
            for (int r = 0; r < 4; ++r) {
                long row = r4 * 4 + r;
                bool yy = (label[row] != 0);
                float tot = 0.f, ms = 0.f;
                for (int c = 0; c < 7; ++c) {
                    float f0, f1;
                    focal_both(logit[(size_t)row * 7 + c], f0, f1);
                    tot += f0;
                    ms  += repr_mask[(size_t)row * 7 + c] ? f1 : 0.f;
                }
                res[r] = yy ? ms : tot;
            }
            reinterpret_cast<float4*>(out)[r4] =
                make_float4(res[0], res[1], res[2], res[3]);
        }
    }

    // scalar tail for B % 4 != 0 (not hit for B = 4M)
    if ((B & 3) && blockIdx.x == 0 && tid == 0) {
        for (long row = (long)(B >> 2) * 4; row < B; ++row) {
            bool yy = (label[row] != 0);
            float tot = 0.f, ms = 0.f;
            for (int c = 0; c < 7; ++c) {
                float f0, f1;
                focal_both(logit[(size_t)row * 7 + c], f0, f1);
                tot += f0;
                ms  += repr_mask[(size_t)row * 7 + c] ? f1 : 0.f;
            }
            out[row] = yy ? ms : tot;
        }
    }
}

extern "C" void kernel_launch(void* const* d_in, const int* in_sizes, int n_in,
                              void* d_out, int out_size, void* d_ws, size_t ws_size,
                              hipStream_t stream) {
    const float* logit     = (const float*)d_in[0];
    const int*   label     = (const int*)d_in[1];
    const int*   repr_mask = (const int*)d_in[2];
    float*       out       = (float*)d_out;

    int B = in_sizes[1];                      // label has B elements
    long chunks = ((long)B + 255) / 256;      // 256-row wave chunks
    int blocks = (int)((chunks + 3) / 4);
    if (blocks < 1) blocks = 1;

    focal_loss_kernel<<<blocks, TPB, 0, stream>>>(logit, label, repr_mask, out, B);
}

// Round 5
// 44.106 us; speedup vs baseline: 1.3981x; 1.0267x over previous
//
#include <hip/hip_runtime.h>

// FocalLoss, 2 categories, negative handling.
// Identity: bce(-x,1-y) == bce(x,y) => focal_neg == focal elementwise.
// loss[row] = (label!=0) ? sum_c f1*mask : sum_c f0.
//
// Round 4 -> 5: occupancy push. Only 20 of 32 staged bytes were consumed:
// stage float2 A[448] (row-A partials, all u) + compact float2 B[192]
// (row-B partials, only crossing u: u%7 in {1,3,5}; index 3*(u/7)+(mu-4)).
// 5 KiB/wave -> 20 KiB/block -> 8 blocks/CU -> 32 waves/CU (was 5/20).
// __launch_bounds__(256,8) caps VGPR at 64; loads are a depth-2 register
// pipeline so that fits without scratch. Writer tracks mu=4u%7 and m=u/7
// incrementally (u+=64 => mu+=4 mod 7; m+=9, +10 on wrap).
// No barriers: wave-private LDS region, same-wave DS pipe is in-order
// (validated rounds 3-4).

#define TPB 256

__device__ __forceinline__ void focal_both(float x, float& f0, float& f1) {
    float a  = fabsf(x);
    float e  = __expf(-a);                    // exp(-|x|) in (0,1]
    float r  = __builtin_amdgcn_rcpf(1.0f + e);
    float q  = e * r;                         // r+q == 1
    float Lg = __logf(1.0f + e);              // = -log r ;  -log q = a+Lg
    float tr = q * q * Lg;                    // focal when pt=r
    float tq = r * r * (a + Lg);              // focal when pt=q
    bool xpos = (x >= 0.0f);
    f1 = xpos ? tr : tq;                      // label==1
    f0 = xpos ? tq : tr;                      // label==0
}

__global__ __launch_bounds__(TPB, 8) void focal_loss_kernel(
    const float* __restrict__ logit,
    const int*   __restrict__ label,
    const int*   __restrict__ repr_mask,
    float*       __restrict__ out,
    int B)
{
    __shared__ float2 sA[4][448];             // 14 KiB: (A0,A1) for every u
    __shared__ float2 sB[4][192];             // 6 KiB: (B0,B1) for crossing u

    const int tid = threadIdx.x;
    const int L   = tid & 63;
    const int w   = tid >> 6;
    const int wc  = blockIdx.x * 4 + w;       // wave chunk: 256 rows
    const long R0 = (long)wc * 256;

    float2* A  = sA[w];
    float2* Bc = sB[w];

    if (R0 + 256 <= B) {
        // ---- fast path: full 256-row chunk = 448 uint4 of logit/mask ----
        const uint4* lg4 = reinterpret_cast<const uint4*>(logit)     + (size_t)wc * 448;
        const uint4* mk4 = reinterpret_cast<const uint4*>(repr_mask) + (size_t)wc * 448;
        int4 lab4 = reinterpret_cast<const int4*>(label)[(size_t)wc * 64 + L];

        // u = k*64 + L ; m = u/7, mu = (4u)%7, tracked incrementally.
        int m  = (L * 9363) >> 16;            // L/7 (exact for L < 448)
        int r0 = L - 7 * m;                   // L%7
        int t4 = 4 * r0;
        int mu = t4 - 7 * ((t4 * 9363) >> 16);// (4L)%7

        uint4 lgc = lg4[L];
        uint4 mkc = mk4[L];
#pragma unroll
        for (int k = 0; k < 7; ++k) {
            uint4 lgn, mkn;
            if (k < 6) {                      // depth-2 pipeline: next tile
                lgn = lg4[(k + 1) * 64 + L];
                mkn = mk4[(k + 1) * 64 + L];
            }
            float4 xf = *reinterpret_cast<float4*>(&lgc);
            float    xs[4] = { xf.x, xf.y, xf.z, xf.w };
            unsigned ms[4] = { mkc.x, mkc.y, mkc.z, mkc.w };

            float A0 = 0.f, A1 = 0.f, B0 = 0.f, B1 = 0.f;
#pragma unroll
            for (int j = 0; j < 4; ++j) {
                float f0, f1;
                focal_both(xs[j], f0, f1);
                float fm = ms[j] ? f1 : 0.0f;
                bool toB = (mu + j) >= 7;     // element spills into row A+1
                A0 += toB ? 0.0f : f0;
                B0 += toB ? f0   : 0.0f;
                A1 += toB ? 0.0f : fm;
                B1 += toB ? fm   : 0.0f;
            }
            A[k * 64 + L] = make_float2(A0, A1);
            if (mu >= 4)                      // crossing u only
                Bc[3 * m + (mu - 4)] = make_float2(B0, B1);

            // u += 64: mu += 4 (mod 7); m += 9 (+1 more when r wraps, r==6 <=> mu==3)
            m += (mu == 3) ? 10 : 9;
            mu += 4; if (mu >= 7) mu -= 7;
            lgc = lgn; mkc = mkn;
        }

        // transpose-combine: reader L consumes A[7L..7L+6], B[3L..3L+2]
        float2 a0 = A[L * 7 + 0];
        float2 a1 = A[L * 7 + 1];
        float2 a2 = A[L * 7 + 2];
        float2 a3 = A[L * 7 + 3];
        float2 a4 = A[L * 7 + 4];
        float2 a5 = A[L * 7 + 5];
        float2 a6 = A[L * 7 + 6];
        float2 b0 = Bc[L * 3 + 0];            // B of u=7L+1
        float2 b1 = Bc[L * 3 + 1];            // B of u=7L+3
        float2 b2 = Bc[L * 3 + 2];            // B of u=7L+5

        float t0_0 = a0.x + a1.x;             float t1_0 = a0.y + a1.y;
        float t0_1 = b0.x + a2.x + a3.x;      float t1_1 = b0.y + a2.y + a3.y;
        float t0_2 = b1.x + a4.x + a5.x;      float t1_2 = b1.y + a4.y + a5.y;
        float t0_3 = b2.x + a6.x;             float t1_3 = b2.y + a6.y;

        float4 res;
        res.x = (lab4.x != 0) ? t1_0 : t0_0;
        res.y = (lab4.y != 0) ? t1_1 : t0_1;
        res.z = (lab4.z != 0) ? t1_2 : t0_2;
        res.w = (lab4.w != 0) ? t1_3 : t0_3;
        reinterpret_cast<float4*>(out)[(size_t)wc * 64 + L] = res;
    } else if (R0 < B) {
        // ---- partial chunk (B % 256): per-lane scalar quad-rows ----
        long r4 = R0 / 4 + L;
        long Q  = B >> 2;
        if (r4 < Q) {
            float res[4];
#pragma unroll
            for (int rr = 0; rr < 4; ++rr) {
                long row = r4 * 4 + rr;
                bool yy = (label[row] != 0);
                float tot = 0.f, ms = 0.f;
                for (int c = 0; c < 7; ++c) {
                    float f0, f1;
                    focal_both(logit[(size_t)row * 7 + c], f0, f1);
                    tot += f0;
                    ms  += repr_mask[(size_t)row * 7 + c] ? f1 : 0.f;
                }
                res[rr] = yy ? ms : tot;
            }
            reinterpret_cast<float4*>(out)[r4] =
                make_float4(res[0], res[1], res[2], res[3]);
        }
    }

    // scalar tail for B % 4 != 0 (not hit for B = 4M)
    if ((B & 3) && blockIdx.x == 0 && tid == 0) {
        for (long row = (long)(B >> 2) * 4; row < B; ++row) {
            bool yy = (label[row] != 0);
            float tot = 0.f, ms = 0.f;
            for (int c = 0; c < 7; ++c) {
                float f0, f1;
                focal_both(logit[(size_t)row * 7 + c], f0, f1);
                tot += f0;
                ms  += repr_mask[(size_t)row * 7 + c] ? f1 : 0.f;
            }
            out[row] = yy ? ms : tot;
        }
    }
}

extern "C" void kernel_launch(void* const* d_in, const int* in_sizes, int n_in,
                              void* d_out, int out_size, void* d_ws, size_t ws_size,
                              hipStream_t stream) {
    const float* logit     = (const float*)d_in[0];
    const int*   label     = (const int*)d_in[1];
    const int*   repr_mask = (const int*)d_in[2];
    float*       out       = (float*)d_out;

    int B = in_sizes[1];                      // label has B elements
    long chunks = ((long)B + 255) / 256;      // 256-row wave chunks
    int blocks = (int)((chunks + 3) / 4);
    if (blocks < 1) blocks = 1;

    focal_loss_kernel<<<blocks, TPB, 0, stream>>>(logit, label, repr_mask, out, B);
}